// Round 16
// baseline (148.312 us; speedup 1.0000x reference)
//
#include <hip/hip_runtime.h>
#include <hip/hip_bf16.h>
#include <math.h>

#define N_NODES 50000
#define N_EDGES 400000
#define F_IN    64
#define HID     128
#define FIN     192   /* F_IN + HID */
#define RU      256   /* 2*HID */
#define BCAP    128   /* bucket capacity; deg~Poisson(8), P(deg>=128)~0 (write-guarded) */

/* ---- ws layout (byte offsets), no aliasing, total 70.75 MB of 256 MiB ----
   counts : int[N]            @ COUNTS_OFF  fillb -> agg1, agg2 (degree)
   bkt    : ushort[N][128]    @ BKT_OFF     fillb -> agg1, agg2
   Wru_bf : bf16[RU][FIN]     @ WRU_OFF     pre -> gemm_r (rows 0-127), gemm_uc (rows 128-255)
   Wc_bf  : bf16[HID][FIN]    @ WC_OFF      pre -> gemm_uc
   s_bf   : bf16[N][HID]      @ SBF_OFF     pre -> agg1, gemm_r (r*s), gemm_uc (states)
   Ax     : bf16[N][F_IN]     @ AX_OFF      agg1 -> gemm_r, gemm_uc
   As     : bf16[N][HID]      @ AS_OFF      agg1 -> gemm_r, gemm_uc (u phase; stays intact)
   Ars    : bf16[N][HID]      @ ARS_OFF     agg2 -> gemm_uc (c phase)
   rs2    : bf16[N][HID]      @ RS2_OFF     gemm_r -> agg2
   x_bf   : bf16[N][F_IN] lives in d_out[0:6.4MB] (dead before gemm_uc writes out1) */
#define COUNTS_OFF 0u
#define BKT_OFF    200064u
#define WRU_OFF    13000064u
#define WC_OFF     13098368u
#define SBF_OFF    13147520u
#define AX_OFF     25947520u
#define AS_OFF     32347520u
#define ARS_OFF    45147520u
#define RS2_OFF    57947520u
#define WS_NEED    70747520u

#define FILLB_BLKS 1563   /* ceil(E/256) */
#define PREW_BLKS  288    /* FIN*(RU+HID)/256 */
#define PREP_BLKS  9375   /* N*(HID+F_IN)/4/256 */

typedef __attribute__((ext_vector_type(8))) short short8;
typedef __attribute__((ext_vector_type(4))) float f32x4;

__device__ __forceinline__ float sigf(float x) { return 1.f / (1.f + expf(-x)); }
__device__ __forceinline__ float bf2f(unsigned short h) {
    return __uint_as_float(((unsigned)h) << 16);
}
__device__ __forceinline__ float bflo(unsigned v) { return __uint_as_float(v << 16); }
__device__ __forceinline__ float bfhi(unsigned v) { return __uint_as_float(v & 0xffff0000u); }
__device__ __forceinline__ unsigned short f2bf(float f) { /* RNE */
    unsigned u = __float_as_uint(f);
    return (unsigned short)((u + 0x7fff + ((u >> 16) & 1)) >> 16);
}
__device__ __forceinline__ unsigned packbf(float lo, float hi) {
    return ((unsigned)f2bf(hi) << 16) | (unsigned)f2bf(lo);
}

/* ------- k_fp: fused bucket-fill + prepW + prep (independent block ranges) ------- */
__global__ __launch_bounds__(256) void k_fp(
        const int* __restrict__ src, const int* __restrict__ dst,
        int* __restrict__ counts, unsigned short* __restrict__ bkt,
        const float* __restrict__ Wru, const float* __restrict__ Wc,
        unsigned short* __restrict__ Wru_bf, unsigned short* __restrict__ Wc_bf,
        const float* __restrict__ states, const float* __restrict__ inputs,
        uint2* __restrict__ s_bf2, uint2* __restrict__ x_bf2) {
    const int blk = blockIdx.x;
    if (blk < FILLB_BLKS) {                /* bucket fill */
        const int e = blk * 256 + threadIdx.x;
        if (e < N_EDGES) {
            const int d = dst[e];
            const int pos = atomicAdd(&counts[d], 1);
            if (pos < BCAP) bkt[(size_t)d * BCAP + pos] = (unsigned short)src[e];
        }
    } else if (blk < FILLB_BLKS + PREW_BLKS) {   /* prepW */
        const int t = (blk - FILLB_BLKS) * 256 + threadIdx.x;
        if (t < FIN * RU) {
            const int k = t >> 8, c = t & 255;
            Wru_bf[c * FIN + k] = f2bf(Wru[t]);
        } else {
            const int tt = t - FIN * RU;
            const int k = tt >> 7, c = tt & 127;
            Wc_bf[c * FIN + k] = f2bf(Wc[tt]);
        }
    } else {                               /* prep: states/inputs -> bf16 */
        const int t = (blk - FILLB_BLKS - PREW_BLKS) * 256 + threadIdx.x;
        if (t < N_NODES * HID / 4) {
            const float4 v = ((const float4*)states)[t];
            s_bf2[t] = make_uint2(packbf(v.x, v.y), packbf(v.z, v.w));
        } else {
            const int j = t - N_NODES * HID / 4;
            const float4 v = ((const float4*)inputs)[j];
            x_bf2[j] = make_uint2(packbf(v.x, v.y), packbf(v.z, v.w));
        }
    }
}

/* ------- agg1: wave/node over buckets; 8-edge main loop; normalize; bf16 out ----- */
__global__ __launch_bounds__(256) void k_agg1(
        const unsigned short* __restrict__ bkt, const int* __restrict__ counts,
        const unsigned* __restrict__ x_u, const uint2* __restrict__ s_u2,
        unsigned* __restrict__ Ax_u, uint2* __restrict__ As_u2) {
    const int n = blockIdx.x * 4 + (threadIdx.x >> 6);
    const int lane = threadIdx.x & 63;
    const int half = lane >> 5;
    const int l = lane & 31;
    const int deg   = counts[n];
    const int start = n * BCAP;
    const int end   = start + (deg < BCAP ? deg : BCAP);
    float ax0 = 0.f, ax1 = 0.f, s0 = 0.f, s1 = 0.f, s2 = 0.f, s3 = 0.f;
    int e = start;
    for (; e + 8 <= end; e += 8) {
        const int ia = bkt[e + half];
        const int ib = bkt[e + 2 + half];
        const int ic = bkt[e + 4 + half];
        const int id = bkt[e + 6 + half];
        const unsigned xa = x_u[(size_t)ia * 32 + l];
        const uint2    sa = s_u2[(size_t)ia * 32 + l];
        const unsigned xb = x_u[(size_t)ib * 32 + l];
        const uint2    sb = s_u2[(size_t)ib * 32 + l];
        const unsigned xc = x_u[(size_t)ic * 32 + l];
        const uint2    sc = s_u2[(size_t)ic * 32 + l];
        const unsigned xd = x_u[(size_t)id * 32 + l];
        const uint2    sd = s_u2[(size_t)id * 32 + l];
        ax0 += bflo(xa); ax1 += bfhi(xa);
        s0 += bflo(sa.x); s1 += bfhi(sa.x); s2 += bflo(sa.y); s3 += bfhi(sa.y);
        ax0 += bflo(xb); ax1 += bfhi(xb);
        s0 += bflo(sb.x); s1 += bfhi(sb.x); s2 += bflo(sb.y); s3 += bfhi(sb.y);
        ax0 += bflo(xc); ax1 += bfhi(xc);
        s0 += bflo(sc.x); s1 += bfhi(sc.x); s2 += bflo(sc.y); s3 += bfhi(sc.y);
        ax0 += bflo(xd); ax1 += bfhi(xd);
        s0 += bflo(sd.x); s1 += bfhi(sd.x); s2 += bflo(sd.y); s3 += bfhi(sd.y);
    }
    if (e + 4 <= end) {
        const int ia = bkt[e + half];
        const int ib = bkt[e + 2 + half];
        const unsigned xa = x_u[(size_t)ia * 32 + l];
        const uint2    sa = s_u2[(size_t)ia * 32 + l];
        const unsigned xb = x_u[(size_t)ib * 32 + l];
        const uint2    sb = s_u2[(size_t)ib * 32 + l];
        ax0 += bflo(xa); ax1 += bfhi(xa);
        s0 += bflo(sa.x); s1 += bfhi(sa.x); s2 += bflo(sa.y); s3 += bfhi(sa.y);
        ax0 += bflo(xb); ax1 += bfhi(xb);
        s0 += bflo(sb.x); s1 += bfhi(sb.x); s2 += bflo(sb.y); s3 += bfhi(sb.y);
        e += 4;
    }
    if (e + 2 <= end) {
        const int ia = bkt[e + half];
        const unsigned xa = x_u[(size_t)ia * 32 + l];
        const uint2    sa = s_u2[(size_t)ia * 32 + l];
        ax0 += bflo(xa); ax1 += bfhi(xa);
        s0 += bflo(sa.x); s1 += bfhi(sa.x); s2 += bflo(sa.y); s3 += bfhi(sa.y);
        e += 2;
    }
    if (e < end && half == 0) {
        const int ia = bkt[e];
        const unsigned xa = x_u[(size_t)ia * 32 + l];
        const uint2    sa = s_u2[(size_t)ia * 32 + l];
        ax0 += bflo(xa); ax1 += bfhi(xa);
        s0 += bflo(sa.x); s1 += bfhi(sa.x); s2 += bflo(sa.y); s3 += bfhi(sa.y);
    }
    ax0 += __shfl_xor(ax0, 32); ax1 += __shfl_xor(ax1, 32);
    s0  += __shfl_xor(s0, 32);  s1  += __shfl_xor(s1, 32);
    s2  += __shfl_xor(s2, 32);  s3  += __shfl_xor(s3, 32);
    if (half == 0) {
        const float inv = 1.f / fmaxf((float)deg, 1.f);
        Ax_u[(size_t)n * 32 + l]  = packbf(ax0 * inv, ax1 * inv);
        As_u2[(size_t)n * 32 + l] = make_uint2(packbf(s0 * inv, s1 * inv),
                                               packbf(s2 * inv, s3 * inv));
    }
}

/* ------- agg2: wave/node over buckets; 8-edge loop of uint2 gathers of rs2 ------- */
__global__ __launch_bounds__(256) void k_agg2(
        const unsigned short* __restrict__ bkt, const int* __restrict__ counts,
        const uint2* __restrict__ rs_u2, uint2* __restrict__ Ars_u2) {
    const int n = blockIdx.x * 4 + (threadIdx.x >> 6);
    const int lane = threadIdx.x & 63;
    const int half = lane >> 5;
    const int l = lane & 31;
    const int deg   = counts[n];
    const int start = n * BCAP;
    const int end   = start + (deg < BCAP ? deg : BCAP);
    float a0 = 0.f, a1 = 0.f, a2 = 0.f, a3 = 0.f;
    int e = start;
    for (; e + 8 <= end; e += 8) {
        const int ia = bkt[e + half];
        const int ib = bkt[e + 2 + half];
        const int ic = bkt[e + 4 + half];
        const int id = bkt[e + 6 + half];
        const uint2 va = rs_u2[(size_t)ia * 32 + l];
        const uint2 vb = rs_u2[(size_t)ib * 32 + l];
        const uint2 vc = rs_u2[(size_t)ic * 32 + l];
        const uint2 vd = rs_u2[(size_t)id * 32 + l];
        a0 += bflo(va.x); a1 += bfhi(va.x); a2 += bflo(va.y); a3 += bfhi(va.y);
        a0 += bflo(vb.x); a1 += bfhi(vb.x); a2 += bflo(vb.y); a3 += bfhi(vb.y);
        a0 += bflo(vc.x); a1 += bfhi(vc.x); a2 += bflo(vc.y); a3 += bfhi(vc.y);
        a0 += bflo(vd.x); a1 += bfhi(vd.x); a2 += bflo(vd.y); a3 += bfhi(vd.y);
    }
    if (e + 4 <= end) {
        const int ia = bkt[e + half];
        const int ib = bkt[e + 2 + half];
        const uint2 va = rs_u2[(size_t)ia * 32 + l];
        const uint2 vb = rs_u2[(size_t)ib * 32 + l];
        a0 += bflo(va.x); a1 += bfhi(va.x); a2 += bflo(va.y); a3 += bfhi(va.y);
        a0 += bflo(vb.x); a1 += bfhi(vb.x); a2 += bflo(vb.y); a3 += bfhi(vb.y);
        e += 4;
    }
    if (e + 2 <= end) {
        const int ia = bkt[e + half];
        const uint2 va = rs_u2[(size_t)ia * 32 + l];
        a0 += bflo(va.x); a1 += bfhi(va.x); a2 += bflo(va.y); a3 += bfhi(va.y);
        e += 2;
    }
    if (e < end && half == 0) {
        const int ia = bkt[e];
        const uint2 va = rs_u2[(size_t)ia * 32 + l];
        a0 += bflo(va.x); a1 += bfhi(va.x); a2 += bflo(va.y); a3 += bfhi(va.y);
    }
    a0 += __shfl_xor(a0, 32); a1 += __shfl_xor(a1, 32);
    a2 += __shfl_xor(a2, 32); a3 += __shfl_xor(a3, 32);
    if (half == 0) {
        const float inv = 1.f / fmaxf((float)deg, 1.f);
        Ars_u2[(size_t)n * 32 + l] = make_uint2(packbf(a0 * inv, a1 * inv),
                                                packbf(a2 * inv, a3 * inv));
    }
}

/* ------- gemm_r (MFMA): [Ax|As] @ Wru[:, :128] -> sigmoid -> rs2 = bf16(r*s) -----
 * grid (391, 2): BM=128 x BN=64, Wt[64][200]=25.6 KB LDS (round-13 proven geom). */
__global__ __launch_bounds__(256, 4) void k_gemm_r(
        const unsigned short* __restrict__ Ax, const unsigned short* __restrict__ As,
        const unsigned short* __restrict__ Wbf, const float* __restrict__ b,
        const unsigned short* __restrict__ s_bf, unsigned short* __restrict__ rs2) {
    __shared__ unsigned short Wt[64][200];
    const int t  = threadIdx.x;
    const int n0 = blockIdx.x * 128;
    const int colbase = blockIdx.y * 64;       /* 0 or 64: r columns only */

    #pragma unroll
    for (int it = 0; it < 6; ++it) {
        const int task = t + 256 * it;
        const int c = task / 24, g = task - c * 24;
        *(uint4*)(&Wt[c][g * 8]) =
            *(const uint4*)(Wbf + (size_t)(colbase + c) * FIN + g * 8);
    }

    const int lane = t & 63, wave = t >> 6;
    const int fr = lane & 15;
    const int fk = (lane >> 4) * 8;

    short8 afr[2][6];
    const short8 zero = {};
    #pragma unroll
    for (int s = 0; s < 2; ++s) {
        const int n = n0 + wave * 32 + s * 16 + fr;
        if (n < N_NODES) {
            const unsigned short* axp = Ax + (size_t)n * F_IN + fk;
            const unsigned short* asp = As + (size_t)n * HID + fk;
            afr[s][0] = *(const short8*)(axp);
            afr[s][1] = *(const short8*)(axp + 32);
            afr[s][2] = *(const short8*)(asp);
            afr[s][3] = *(const short8*)(asp + 32);
            afr[s][4] = *(const short8*)(asp + 64);
            afr[s][5] = *(const short8*)(asp + 96);
        } else {
            #pragma unroll
            for (int j = 0; j < 6; ++j) afr[s][j] = zero;
        }
    }
    __syncthreads();

    f32x4 acc[2][4] = {};
    #pragma unroll
    for (int k0 = 0; k0 < 6; ++k0) {
        #pragma unroll
        for (int ct = 0; ct < 4; ++ct) {
            const short8 bw = *(const short8*)(&Wt[ct * 16 + fr][fk + k0 * 32]);
            acc[0][ct] = __builtin_amdgcn_mfma_f32_16x16x32_bf16(afr[0][k0], bw, acc[0][ct], 0, 0, 0);
            acc[1][ct] = __builtin_amdgcn_mfma_f32_16x16x32_bf16(afr[1][k0], bw, acc[1][ct], 0, 0, 0);
        }
    }

    #pragma unroll
    for (int s = 0; s < 2; ++s) {
        const int rbase = n0 + wave * 32 + s * 16 + (lane >> 4) * 4;
        #pragma unroll
        for (int ct = 0; ct < 4; ++ct) {
            const int col = colbase + ct * 16 + fr;     /* 0..127 */
            const float bias = b[col];
            #pragma unroll
            for (int i = 0; i < 4; ++i) {
                const int n = rbase + i;
                if (n < N_NODES) {
                    const size_t idx = (size_t)n * HID + col;
                    const float r = sigf(acc[s][ct][i] + bias);
                    rs2[idx] = f2bf(r * bf2f(s_bf[idx]));
                }
            }
        }
    }
}

/* ------- gemm_uc (MFMA, two-phase): u stays in registers -------
 * grid (391, 2): BM=128 x BN=64, 4 waves x 2 stripes. Halves the Wt stagings
 * vs BM=64 (round-15). sigmoid overwrites uacc in place (no uu array).
 * phase 1: Wt <- Wru rows 128+colbase.., A=[Ax|As] -> sigmoid -> uacc
 * phase 2: Wt <- Wc rows colbase.., Ars frags      -> tanh -> gate -> out.  */
__global__ __launch_bounds__(256, 3) void k_gemm_uc(
        const unsigned short* __restrict__ Ax, const unsigned short* __restrict__ As,
        const unsigned short* __restrict__ Ars,
        const unsigned short* __restrict__ Wru_bf, const unsigned short* __restrict__ Wc_bf,
        const float* __restrict__ b_ru, const float* __restrict__ b_c,
        const unsigned short* __restrict__ st_bf,
        float* __restrict__ out1, float* __restrict__ out2) {
    __shared__ unsigned short Wt[64][200];
    const int t  = threadIdx.x;
    const int n0 = blockIdx.x * 128;
    const int colbase = blockIdx.y * 64;
    const int lane = t & 63, wave = t >> 6;
    const int fr = lane & 15;
    const int fk = (lane >> 4) * 8;
    const short8 zero = {};

    /* ---- phase 1: u = sigmoid([Ax|As] @ Wru[:,128+colbase..] + b_ru) ---- */
    #pragma unroll
    for (int it = 0; it < 6; ++it) {
        const int task = t + 256 * it;
        const int c = task / 24, g = task - c * 24;
        *(uint4*)(&Wt[c][g * 8]) =
            *(const uint4*)(Wru_bf + (size_t)(128 + colbase + c) * FIN + g * 8);
    }

    short8 axf[2][2], sf[2][4];
    #pragma unroll
    for (int s = 0; s < 2; ++s) {
        const int n = n0 + wave * 32 + s * 16 + fr;
        if (n < N_NODES) {
            const unsigned short* axp = Ax + (size_t)n * F_IN + fk;
            const unsigned short* asp = As + (size_t)n * HID + fk;
            axf[s][0] = *(const short8*)(axp);
            axf[s][1] = *(const short8*)(axp + 32);
            sf[s][0] = *(const short8*)(asp);
            sf[s][1] = *(const short8*)(asp + 32);
            sf[s][2] = *(const short8*)(asp + 64);
            sf[s][3] = *(const short8*)(asp + 96);
        } else {
            axf[s][0] = zero; axf[s][1] = zero;
            #pragma unroll
            for (int j = 0; j < 4; ++j) sf[s][j] = zero;
        }
    }
    __syncthreads();

    f32x4 uacc[2][4] = {};
    #pragma unroll
    for (int k0 = 0; k0 < 6; ++k0) {
        #pragma unroll
        for (int s = 0; s < 2; ++s) {
            const short8 a = (k0 < 2) ? axf[s][k0] : sf[s][k0 - 2];
            #pragma unroll
            for (int ct = 0; ct < 4; ++ct) {
                const short8 bw = *(const short8*)(&Wt[ct * 16 + fr][fk + k0 * 32]);
                uacc[s][ct] = __builtin_amdgcn_mfma_f32_16x16x32_bf16(a, bw, uacc[s][ct], 0, 0, 0);
            }
        }
    }
    /* sigmoid in place: uacc becomes u */
    #pragma unroll
    for (int s = 0; s < 2; ++s)
        #pragma unroll
        for (int ct = 0; ct < 4; ++ct) {
            const float bias = b_ru[128 + colbase + ct * 16 + fr];
            #pragma unroll
            for (int i = 0; i < 4; ++i)
                uacc[s][ct][i] = sigf(uacc[s][ct][i] + bias);
        }
    __syncthreads();   /* all waves done reading Wt */

    /* ---- phase 2: c = tanh([Ax|Ars] @ Wc + b_c); gate ---- */
    #pragma unroll
    for (int it = 0; it < 6; ++it) {
        const int task = t + 256 * it;
        const int c = task / 24, g = task - c * 24;
        *(uint4*)(&Wt[c][g * 8]) =
            *(const uint4*)(Wc_bf + (size_t)(colbase + c) * FIN + g * 8);
    }
    #pragma unroll
    for (int s = 0; s < 2; ++s) {
        const int n = n0 + wave * 32 + s * 16 + fr;
        if (n < N_NODES) {
            const unsigned short* arp = Ars + (size_t)n * HID + fk;
            sf[s][0] = *(const short8*)(arp);
            sf[s][1] = *(const short8*)(arp + 32);
            sf[s][2] = *(const short8*)(arp + 64);
            sf[s][3] = *(const short8*)(arp + 96);
        }
    }
    __syncthreads();

    f32x4 cacc[2][4] = {};
    #pragma unroll
    for (int k0 = 0; k0 < 6; ++k0) {
        #pragma unroll
        for (int s = 0; s < 2; ++s) {
            const short8 a = (k0 < 2) ? axf[s][k0] : sf[s][k0 - 2];
            #pragma unroll
            for (int ct = 0; ct < 4; ++ct) {
                const short8 bw = *(const short8*)(&Wt[ct * 16 + fr][fk + k0 * 32]);
                cacc[s][ct] = __builtin_amdgcn_mfma_f32_16x16x32_bf16(a, bw, cacc[s][ct], 0, 0, 0);
            }
        }
    }

    #pragma unroll
    for (int s = 0; s < 2; ++s) {
        const int rbase = n0 + wave * 32 + s * 16 + (lane >> 4) * 4;
        #pragma unroll
        for (int ct = 0; ct < 4; ++ct) {
            const int col = colbase + ct * 16 + fr;
            const float bias = b_c[col];
            #pragma unroll
            for (int i = 0; i < 4; ++i) {
                const int nn = rbase + i;
                if (nn < N_NODES) {
                    const size_t idx = (size_t)nn * HID + col;
                    const float c  = tanhf(cacc[s][ct][i] + bias);
                    const float u  = uacc[s][ct][i];
                    const float st = bf2f(st_bf[idx]);
                    const float ns = u * st + (1.f - u) * c;
                    out1[idx] = ns;
                    out2[idx] = ns;
                }
            }
        }
    }
}

extern "C" void kernel_launch(void* const* d_in, const int* in_sizes, int n_in,
                              void* d_out, int out_size, void* d_ws, size_t ws_size,
                              hipStream_t stream) {
    const float* inputs = (const float*)d_in[0];
    const float* states = (const float*)d_in[1];
    const int*   ei     = (const int*)d_in[2];
    const float* W_ru   = (const float*)d_in[3];
    const float* b_ru   = (const float*)d_in[4];
    const float* W_c    = (const float*)d_in[5];
    const float* b_c    = (const float*)d_in[6];

    float* out  = (float*)d_out;
    float* out1 = out;                             /* x_bf early, new_state at end */
    float* out2 = out + (size_t)N_NODES * HID;

    char* ws = (char*)d_ws;
    int*            counts = (int*)(ws + COUNTS_OFF);
    unsigned short* bkt    = (unsigned short*)(ws + BKT_OFF);
    unsigned short* Wru_bf = (unsigned short*)(ws + WRU_OFF);
    unsigned short* Wc_bf  = (unsigned short*)(ws + WC_OFF);
    unsigned short* s_bf   = (unsigned short*)(ws + SBF_OFF);
    unsigned short* Ax     = (unsigned short*)(ws + AX_OFF);
    unsigned short* As     = (unsigned short*)(ws + AS_OFF);
    unsigned short* Ars    = (unsigned short*)(ws + ARS_OFF);
    unsigned short* rs2    = (unsigned short*)(ws + RS2_OFF);
    unsigned short* x_bf   = (unsigned short*)d_out;           /* first 6.4MB of out1 */

    (void)ws_size;  /* harness ws = 256 MiB (observed poison writes); WS_NEED = 70.75 MB */

    const int* src = ei;
    const int* dst = ei + N_EDGES;

    const int agg_grid = N_NODES / 4;              /* 12500 */
    const int gr_grid  = (N_NODES + 127) / 128;    /* 391   */
    const int fp_grid  = FILLB_BLKS + PREW_BLKS + PREP_BLKS;   /* 11226 */

    hipMemsetAsync(counts, 0, N_NODES * sizeof(int), stream);
    k_fp    <<<fp_grid, 256, 0, stream>>>(src, dst, counts, bkt, W_ru, W_c,
                                          Wru_bf, Wc_bf, states, inputs,
                                          (uint2*)s_bf, (uint2*)x_bf);
    k_agg1  <<<agg_grid, 256, 0, stream>>>(bkt, counts, (const unsigned*)x_bf,
                                           (const uint2*)s_bf,
                                           (unsigned*)Ax, (uint2*)As);
    k_gemm_r<<<dim3(gr_grid, 2), 256, 0, stream>>>(Ax, As, Wru_bf, b_ru, s_bf, rs2);
    k_agg2  <<<agg_grid, 256, 0, stream>>>(bkt, counts, (const uint2*)rs2,
                                           (uint2*)Ars);
    k_gemm_uc<<<dim3(gr_grid, 2), 256, 0, stream>>>(Ax, As, Ars, Wru_bf, Wc_bf,
                                                    b_ru, b_c, s_bf, out1, out2);
}

// Round 17
// 139.323 us; speedup vs baseline: 1.0645x; 1.0645x over previous
//
#include <hip/hip_runtime.h>
#include <hip/hip_bf16.h>
#include <math.h>

#define N_NODES 50000
#define N_EDGES 400000
#define F_IN    64
#define HID     128
#define FIN     192   /* F_IN + HID */
#define RU      256   /* 2*HID */
#define BCAP    128   /* bucket capacity; deg~Poisson(8), P(deg>=128)~0 (write-guarded) */

/* ---- ws layout (byte offsets), no aliasing, total 70.75 MB of 256 MiB ----
   counts : int[N]            @ COUNTS_OFF  fillb -> agg1, agg2 (degree)
   bkt    : ushort[N][128]    @ BKT_OFF     fillb -> agg1, agg2
   Wru_bf : bf16[RU][FIN]     @ WRU_OFF     pre -> gemm_r (rows 0-127), gemm_uc (rows 128-255)
   Wc_bf  : bf16[HID][FIN]    @ WC_OFF      pre -> gemm_uc
   s_bf   : bf16[N][HID]      @ SBF_OFF     pre -> agg1, gemm_r (r*s), gemm_uc (states)
   Ax     : bf16[N][F_IN]     @ AX_OFF      agg1 -> gemm_r, gemm_uc
   As     : bf16[N][HID]      @ AS_OFF      agg1 -> gemm_r, gemm_uc (u phase; stays intact)
   Ars    : bf16[N][HID]      @ ARS_OFF     agg2 -> gemm_uc (c phase)
   rs2    : bf16[N][HID]      @ RS2_OFF     gemm_r -> agg2
   x_bf   : bf16[N][F_IN] lives in d_out[0:6.4MB] (dead before gemm_uc writes out1) */
#define COUNTS_OFF 0u
#define BKT_OFF    200064u
#define WRU_OFF    13000064u
#define WC_OFF     13098368u
#define SBF_OFF    13147520u
#define AX_OFF     25947520u
#define AS_OFF     32347520u
#define ARS_OFF    45147520u
#define RS2_OFF    57947520u
#define WS_NEED    70747520u

#define FILLB_BLKS 1563   /* ceil(E/256) */
#define PREW_BLKS  288    /* FIN*(RU+HID)/256 */
#define PREP_BLKS  9375   /* N*(HID+F_IN)/4/256 */

typedef __attribute__((ext_vector_type(8))) short short8;
typedef __attribute__((ext_vector_type(4))) float f32x4;

__device__ __forceinline__ float sigf(float x) { return 1.f / (1.f + expf(-x)); }
__device__ __forceinline__ float bf2f(unsigned short h) {
    return __uint_as_float(((unsigned)h) << 16);
}
__device__ __forceinline__ float bflo(unsigned v) { return __uint_as_float(v << 16); }
__device__ __forceinline__ float bfhi(unsigned v) { return __uint_as_float(v & 0xffff0000u); }
__device__ __forceinline__ unsigned short f2bf(float f) { /* RNE */
    unsigned u = __float_as_uint(f);
    return (unsigned short)((u + 0x7fff + ((u >> 16) & 1)) >> 16);
}
__device__ __forceinline__ unsigned packbf(float lo, float hi) {
    return ((unsigned)f2bf(hi) << 16) | (unsigned)f2bf(lo);
}

/* ------- k_fp: fused bucket-fill + prepW + prep (independent block ranges) ------- */
__global__ __launch_bounds__(256) void k_fp(
        const int* __restrict__ src, const int* __restrict__ dst,
        int* __restrict__ counts, unsigned short* __restrict__ bkt,
        const float* __restrict__ Wru, const float* __restrict__ Wc,
        unsigned short* __restrict__ Wru_bf, unsigned short* __restrict__ Wc_bf,
        const float* __restrict__ states, const float* __restrict__ inputs,
        uint2* __restrict__ s_bf2, uint2* __restrict__ x_bf2) {
    const int blk = blockIdx.x;
    if (blk < FILLB_BLKS) {                /* bucket fill */
        const int e = blk * 256 + threadIdx.x;
        if (e < N_EDGES) {
            const int d = dst[e];
            const int pos = atomicAdd(&counts[d], 1);
            if (pos < BCAP) bkt[(size_t)d * BCAP + pos] = (unsigned short)src[e];
        }
    } else if (blk < FILLB_BLKS + PREW_BLKS) {   /* prepW */
        const int t = (blk - FILLB_BLKS) * 256 + threadIdx.x;
        if (t < FIN * RU) {
            const int k = t >> 8, c = t & 255;
            Wru_bf[c * FIN + k] = f2bf(Wru[t]);
        } else {
            const int tt = t - FIN * RU;
            const int k = tt >> 7, c = tt & 127;
            Wc_bf[c * FIN + k] = f2bf(Wc[tt]);
        }
    } else {                               /* prep: states/inputs -> bf16 */
        const int t = (blk - FILLB_BLKS - PREW_BLKS) * 256 + threadIdx.x;
        if (t < N_NODES * HID / 4) {
            const float4 v = ((const float4*)states)[t];
            s_bf2[t] = make_uint2(packbf(v.x, v.y), packbf(v.z, v.w));
        } else {
            const int j = t - N_NODES * HID / 4;
            const float4 v = ((const float4*)inputs)[j];
            x_bf2[j] = make_uint2(packbf(v.x, v.y), packbf(v.z, v.w));
        }
    }
}

/* ------- agg1: wave/node over buckets; 8-edge main loop; normalize; bf16 out ----- */
__global__ __launch_bounds__(256) void k_agg1(
        const unsigned short* __restrict__ bkt, const int* __restrict__ counts,
        const unsigned* __restrict__ x_u, const uint2* __restrict__ s_u2,
        unsigned* __restrict__ Ax_u, uint2* __restrict__ As_u2) {
    const int n = blockIdx.x * 4 + (threadIdx.x >> 6);
    const int lane = threadIdx.x & 63;
    const int half = lane >> 5;
    const int l = lane & 31;
    const int deg   = counts[n];
    const int start = n * BCAP;
    const int end   = start + (deg < BCAP ? deg : BCAP);
    float ax0 = 0.f, ax1 = 0.f, s0 = 0.f, s1 = 0.f, s2 = 0.f, s3 = 0.f;
    int e = start;
    for (; e + 8 <= end; e += 8) {
        const int ia = bkt[e + half];
        const int ib = bkt[e + 2 + half];
        const int ic = bkt[e + 4 + half];
        const int id = bkt[e + 6 + half];
        const unsigned xa = x_u[(size_t)ia * 32 + l];
        const uint2    sa = s_u2[(size_t)ia * 32 + l];
        const unsigned xb = x_u[(size_t)ib * 32 + l];
        const uint2    sb = s_u2[(size_t)ib * 32 + l];
        const unsigned xc = x_u[(size_t)ic * 32 + l];
        const uint2    sc = s_u2[(size_t)ic * 32 + l];
        const unsigned xd = x_u[(size_t)id * 32 + l];
        const uint2    sd = s_u2[(size_t)id * 32 + l];
        ax0 += bflo(xa); ax1 += bfhi(xa);
        s0 += bflo(sa.x); s1 += bfhi(sa.x); s2 += bflo(sa.y); s3 += bfhi(sa.y);
        ax0 += bflo(xb); ax1 += bfhi(xb);
        s0 += bflo(sb.x); s1 += bfhi(sb.x); s2 += bflo(sb.y); s3 += bfhi(sb.y);
        ax0 += bflo(xc); ax1 += bfhi(xc);
        s0 += bflo(sc.x); s1 += bfhi(sc.x); s2 += bflo(sc.y); s3 += bfhi(sc.y);
        ax0 += bflo(xd); ax1 += bfhi(xd);
        s0 += bflo(sd.x); s1 += bfhi(sd.x); s2 += bflo(sd.y); s3 += bfhi(sd.y);
    }
    if (e + 4 <= end) {
        const int ia = bkt[e + half];
        const int ib = bkt[e + 2 + half];
        const unsigned xa = x_u[(size_t)ia * 32 + l];
        const uint2    sa = s_u2[(size_t)ia * 32 + l];
        const unsigned xb = x_u[(size_t)ib * 32 + l];
        const uint2    sb = s_u2[(size_t)ib * 32 + l];
        ax0 += bflo(xa); ax1 += bfhi(xa);
        s0 += bflo(sa.x); s1 += bfhi(sa.x); s2 += bflo(sa.y); s3 += bfhi(sa.y);
        ax0 += bflo(xb); ax1 += bfhi(xb);
        s0 += bflo(sb.x); s1 += bfhi(sb.x); s2 += bflo(sb.y); s3 += bfhi(sb.y);
        e += 4;
    }
    if (e + 2 <= end) {
        const int ia = bkt[e + half];
        const unsigned xa = x_u[(size_t)ia * 32 + l];
        const uint2    sa = s_u2[(size_t)ia * 32 + l];
        ax0 += bflo(xa); ax1 += bfhi(xa);
        s0 += bflo(sa.x); s1 += bfhi(sa.x); s2 += bflo(sa.y); s3 += bfhi(sa.y);
        e += 2;
    }
    if (e < end && half == 0) {
        const int ia = bkt[e];
        const unsigned xa = x_u[(size_t)ia * 32 + l];
        const uint2    sa = s_u2[(size_t)ia * 32 + l];
        ax0 += bflo(xa); ax1 += bfhi(xa);
        s0 += bflo(sa.x); s1 += bfhi(sa.x); s2 += bflo(sa.y); s3 += bfhi(sa.y);
    }
    ax0 += __shfl_xor(ax0, 32); ax1 += __shfl_xor(ax1, 32);
    s0  += __shfl_xor(s0, 32);  s1  += __shfl_xor(s1, 32);
    s2  += __shfl_xor(s2, 32);  s3  += __shfl_xor(s3, 32);
    if (half == 0) {
        const float inv = 1.f / fmaxf((float)deg, 1.f);
        Ax_u[(size_t)n * 32 + l]  = packbf(ax0 * inv, ax1 * inv);
        As_u2[(size_t)n * 32 + l] = make_uint2(packbf(s0 * inv, s1 * inv),
                                               packbf(s2 * inv, s3 * inv));
    }
}

/* ------- agg2: wave/node over buckets; 8-edge loop of uint2 gathers of rs2 ------- */
__global__ __launch_bounds__(256) void k_agg2(
        const unsigned short* __restrict__ bkt, const int* __restrict__ counts,
        const uint2* __restrict__ rs_u2, uint2* __restrict__ Ars_u2) {
    const int n = blockIdx.x * 4 + (threadIdx.x >> 6);
    const int lane = threadIdx.x & 63;
    const int half = lane >> 5;
    const int l = lane & 31;
    const int deg   = counts[n];
    const int start = n * BCAP;
    const int end   = start + (deg < BCAP ? deg : BCAP);
    float a0 = 0.f, a1 = 0.f, a2 = 0.f, a3 = 0.f;
    int e = start;
    for (; e + 8 <= end; e += 8) {
        const int ia = bkt[e + half];
        const int ib = bkt[e + 2 + half];
        const int ic = bkt[e + 4 + half];
        const int id = bkt[e + 6 + half];
        const uint2 va = rs_u2[(size_t)ia * 32 + l];
        const uint2 vb = rs_u2[(size_t)ib * 32 + l];
        const uint2 vc = rs_u2[(size_t)ic * 32 + l];
        const uint2 vd = rs_u2[(size_t)id * 32 + l];
        a0 += bflo(va.x); a1 += bfhi(va.x); a2 += bflo(va.y); a3 += bfhi(va.y);
        a0 += bflo(vb.x); a1 += bfhi(vb.x); a2 += bflo(vb.y); a3 += bfhi(vb.y);
        a0 += bflo(vc.x); a1 += bfhi(vc.x); a2 += bflo(vc.y); a3 += bfhi(vc.y);
        a0 += bflo(vd.x); a1 += bfhi(vd.x); a2 += bflo(vd.y); a3 += bfhi(vd.y);
    }
    if (e + 4 <= end) {
        const int ia = bkt[e + half];
        const int ib = bkt[e + 2 + half];
        const uint2 va = rs_u2[(size_t)ia * 32 + l];
        const uint2 vb = rs_u2[(size_t)ib * 32 + l];
        a0 += bflo(va.x); a1 += bfhi(va.x); a2 += bflo(va.y); a3 += bfhi(va.y);
        a0 += bflo(vb.x); a1 += bfhi(vb.x); a2 += bflo(vb.y); a3 += bfhi(vb.y);
        e += 4;
    }
    if (e + 2 <= end) {
        const int ia = bkt[e + half];
        const uint2 va = rs_u2[(size_t)ia * 32 + l];
        a0 += bflo(va.x); a1 += bfhi(va.x); a2 += bflo(va.y); a3 += bfhi(va.y);
        e += 2;
    }
    if (e < end && half == 0) {
        const int ia = bkt[e];
        const uint2 va = rs_u2[(size_t)ia * 32 + l];
        a0 += bflo(va.x); a1 += bfhi(va.x); a2 += bflo(va.y); a3 += bfhi(va.y);
    }
    a0 += __shfl_xor(a0, 32); a1 += __shfl_xor(a1, 32);
    a2 += __shfl_xor(a2, 32); a3 += __shfl_xor(a3, 32);
    if (half == 0) {
        const float inv = 1.f / fmaxf((float)deg, 1.f);
        Ars_u2[(size_t)n * 32 + l] = make_uint2(packbf(a0 * inv, a1 * inv),
                                                packbf(a2 * inv, a3 * inv));
    }
}

/* ------- gemm_r (MFMA): [Ax|As] @ Wru[:, :128] -> sigmoid -> rs2 = bf16(r*s) -----
 * grid (391, 2): BM=128 x BN=64, Wt[64][200]=25.6 KB LDS (round-13 proven geom). */
__global__ __launch_bounds__(256, 4) void k_gemm_r(
        const unsigned short* __restrict__ Ax, const unsigned short* __restrict__ As,
        const unsigned short* __restrict__ Wbf, const float* __restrict__ b,
        const unsigned short* __restrict__ s_bf, unsigned short* __restrict__ rs2) {
    __shared__ unsigned short Wt[64][200];
    const int t  = threadIdx.x;
    const int n0 = blockIdx.x * 128;
    const int colbase = blockIdx.y * 64;       /* 0 or 64: r columns only */

    #pragma unroll
    for (int it = 0; it < 6; ++it) {
        const int task = t + 256 * it;
        const int c = task / 24, g = task - c * 24;
        *(uint4*)(&Wt[c][g * 8]) =
            *(const uint4*)(Wbf + (size_t)(colbase + c) * FIN + g * 8);
    }

    const int lane = t & 63, wave = t >> 6;
    const int fr = lane & 15;
    const int fk = (lane >> 4) * 8;

    short8 afr[2][6];
    const short8 zero = {};
    #pragma unroll
    for (int s = 0; s < 2; ++s) {
        const int n = n0 + wave * 32 + s * 16 + fr;
        if (n < N_NODES) {
            const unsigned short* axp = Ax + (size_t)n * F_IN + fk;
            const unsigned short* asp = As + (size_t)n * HID + fk;
            afr[s][0] = *(const short8*)(axp);
            afr[s][1] = *(const short8*)(axp + 32);
            afr[s][2] = *(const short8*)(asp);
            afr[s][3] = *(const short8*)(asp + 32);
            afr[s][4] = *(const short8*)(asp + 64);
            afr[s][5] = *(const short8*)(asp + 96);
        } else {
            #pragma unroll
            for (int j = 0; j < 6; ++j) afr[s][j] = zero;
        }
    }
    __syncthreads();

    f32x4 acc[2][4] = {};
    #pragma unroll
    for (int k0 = 0; k0 < 6; ++k0) {
        #pragma unroll
        for (int ct = 0; ct < 4; ++ct) {
            const short8 bw = *(const short8*)(&Wt[ct * 16 + fr][fk + k0 * 32]);
            acc[0][ct] = __builtin_amdgcn_mfma_f32_16x16x32_bf16(afr[0][k0], bw, acc[0][ct], 0, 0, 0);
            acc[1][ct] = __builtin_amdgcn_mfma_f32_16x16x32_bf16(afr[1][k0], bw, acc[1][ct], 0, 0, 0);
        }
    }

    #pragma unroll
    for (int s = 0; s < 2; ++s) {
        const int rbase = n0 + wave * 32 + s * 16 + (lane >> 4) * 4;
        #pragma unroll
        for (int ct = 0; ct < 4; ++ct) {
            const int col = colbase + ct * 16 + fr;     /* 0..127 */
            const float bias = b[col];
            #pragma unroll
            for (int i = 0; i < 4; ++i) {
                const int n = rbase + i;
                if (n < N_NODES) {
                    const size_t idx = (size_t)n * HID + col;
                    const float r = sigf(acc[s][ct][i] + bias);
                    rs2[idx] = f2bf(r * bf2f(s_bf[idx]));
                }
            }
        }
    }
}

/* ------- gemm_uc (MFMA, two-phase): u stays in registers -------
 * grid (782, 2): BM=64 x BN=64, 4 waves, one 16-row stripe each (round-15
 * proven: the 1564-block grid is what hides the two-phase latency; round-16's
 * BM=128/782-block variant dropped to 20% occupancy and cost +19 us).
 * phase 1: Wt <- Wru rows 128+colbase.., A=[Ax|As] -> sigmoid -> uu (regs)
 * phase 2: Wt <- Wc rows colbase.., Ars frags      -> tanh -> gate -> out.  */
__global__ __launch_bounds__(256) void k_gemm_uc(
        const unsigned short* __restrict__ Ax, const unsigned short* __restrict__ As,
        const unsigned short* __restrict__ Ars,
        const unsigned short* __restrict__ Wru_bf, const unsigned short* __restrict__ Wc_bf,
        const float* __restrict__ b_ru, const float* __restrict__ b_c,
        const unsigned short* __restrict__ st_bf,
        float* __restrict__ out1, float* __restrict__ out2) {
    __shared__ unsigned short Wt[64][200];
    const int t  = threadIdx.x;
    const int n0 = blockIdx.x * 64;
    const int colbase = blockIdx.y * 64;
    const int lane = t & 63, wave = t >> 6;
    const int fr = lane & 15;
    const int fk = (lane >> 4) * 8;
    const int n = n0 + wave * 16 + fr;
    const short8 zero = {};

    /* ---- phase 1: u = sigmoid([Ax|As] @ Wru[:,128+colbase..] + b_ru) ---- */
    #pragma unroll
    for (int it = 0; it < 6; ++it) {
        const int task = t + 256 * it;
        const int c = task / 24, g = task - c * 24;
        *(uint4*)(&Wt[c][g * 8]) =
            *(const uint4*)(Wru_bf + (size_t)(128 + colbase + c) * FIN + g * 8);
    }

    short8 axf0 = zero, axf1 = zero, sf[4] = {zero, zero, zero, zero};
    if (n < N_NODES) {
        const unsigned short* axp = Ax + (size_t)n * F_IN + fk;
        const unsigned short* asp = As + (size_t)n * HID + fk;
        axf0 = *(const short8*)(axp);
        axf1 = *(const short8*)(axp + 32);
        sf[0] = *(const short8*)(asp);
        sf[1] = *(const short8*)(asp + 32);
        sf[2] = *(const short8*)(asp + 64);
        sf[3] = *(const short8*)(asp + 96);
    }
    __syncthreads();

    f32x4 uacc[4] = {};
    #pragma unroll
    for (int k0 = 0; k0 < 6; ++k0) {
        const short8 a = (k0 == 0) ? axf0 : (k0 == 1) ? axf1 : sf[k0 - 2];
        #pragma unroll
        for (int ct = 0; ct < 4; ++ct) {
            const short8 bw = *(const short8*)(&Wt[ct * 16 + fr][fk + k0 * 32]);
            uacc[ct] = __builtin_amdgcn_mfma_f32_16x16x32_bf16(a, bw, uacc[ct], 0, 0, 0);
        }
    }
    float uu[4][4];
    #pragma unroll
    for (int ct = 0; ct < 4; ++ct) {
        const float bias = b_ru[128 + colbase + ct * 16 + fr];
        #pragma unroll
        for (int i = 0; i < 4; ++i) uu[ct][i] = sigf(uacc[ct][i] + bias);
    }
    __syncthreads();   /* all waves done reading Wt */

    /* ---- phase 2: c = tanh([Ax|Ars] @ Wc + b_c); gate ---- */
    #pragma unroll
    for (int it = 0; it < 6; ++it) {
        const int task = t + 256 * it;
        const int c = task / 24, g = task - c * 24;
        *(uint4*)(&Wt[c][g * 8]) =
            *(const uint4*)(Wc_bf + (size_t)(colbase + c) * FIN + g * 8);
    }
    if (n < N_NODES) {
        const unsigned short* arp = Ars + (size_t)n * HID + fk;
        sf[0] = *(const short8*)(arp);
        sf[1] = *(const short8*)(arp + 32);
        sf[2] = *(const short8*)(arp + 64);
        sf[3] = *(const short8*)(arp + 96);
    }
    __syncthreads();

    f32x4 cacc[4] = {};
    #pragma unroll
    for (int k0 = 0; k0 < 6; ++k0) {
        const short8 a = (k0 == 0) ? axf0 : (k0 == 1) ? axf1 : sf[k0 - 2];
        #pragma unroll
        for (int ct = 0; ct < 4; ++ct) {
            const short8 bw = *(const short8*)(&Wt[ct * 16 + fr][fk + k0 * 32]);
            cacc[ct] = __builtin_amdgcn_mfma_f32_16x16x32_bf16(a, bw, cacc[ct], 0, 0, 0);
        }
    }

    const int rbase = n0 + wave * 16 + (lane >> 4) * 4;
    #pragma unroll
    for (int ct = 0; ct < 4; ++ct) {
        const int col = colbase + ct * 16 + fr;
        const float bias = b_c[col];
        #pragma unroll
        for (int i = 0; i < 4; ++i) {
            const int nn = rbase + i;
            if (nn < N_NODES) {
                const size_t idx = (size_t)nn * HID + col;
                const float c  = tanhf(cacc[ct][i] + bias);
                const float u  = uu[ct][i];
                const float st = bf2f(st_bf[idx]);
                const float ns = u * st + (1.f - u) * c;
                out1[idx] = ns;
                out2[idx] = ns;
            }
        }
    }
}

extern "C" void kernel_launch(void* const* d_in, const int* in_sizes, int n_in,
                              void* d_out, int out_size, void* d_ws, size_t ws_size,
                              hipStream_t stream) {
    const float* inputs = (const float*)d_in[0];
    const float* states = (const float*)d_in[1];
    const int*   ei     = (const int*)d_in[2];
    const float* W_ru   = (const float*)d_in[3];
    const float* b_ru   = (const float*)d_in[4];
    const float* W_c    = (const float*)d_in[5];
    const float* b_c    = (const float*)d_in[6];

    float* out  = (float*)d_out;
    float* out1 = out;                             /* x_bf early, new_state at end */
    float* out2 = out + (size_t)N_NODES * HID;

    char* ws = (char*)d_ws;
    int*            counts = (int*)(ws + COUNTS_OFF);
    unsigned short* bkt    = (unsigned short*)(ws + BKT_OFF);
    unsigned short* Wru_bf = (unsigned short*)(ws + WRU_OFF);
    unsigned short* Wc_bf  = (unsigned short*)(ws + WC_OFF);
    unsigned short* s_bf   = (unsigned short*)(ws + SBF_OFF);
    unsigned short* Ax     = (unsigned short*)(ws + AX_OFF);
    unsigned short* As     = (unsigned short*)(ws + AS_OFF);
    unsigned short* Ars    = (unsigned short*)(ws + ARS_OFF);
    unsigned short* rs2    = (unsigned short*)(ws + RS2_OFF);
    unsigned short* x_bf   = (unsigned short*)d_out;           /* first 6.4MB of out1 */

    (void)ws_size;  /* harness ws = 256 MiB (observed poison writes); WS_NEED = 70.75 MB */

    const int* src = ei;
    const int* dst = ei + N_EDGES;

    const int agg_grid = N_NODES / 4;              /* 12500 */
    const int gr_grid  = (N_NODES + 127) / 128;    /* 391   */
    const int guc_grid = (N_NODES + 63) / 64;      /* 782   */
    const int fp_grid  = FILLB_BLKS + PREW_BLKS + PREP_BLKS;   /* 11226 */

    hipMemsetAsync(counts, 0, N_NODES * sizeof(int), stream);
    k_fp    <<<fp_grid, 256, 0, stream>>>(src, dst, counts, bkt, W_ru, W_c,
                                          Wru_bf, Wc_bf, states, inputs,
                                          (uint2*)s_bf, (uint2*)x_bf);
    k_agg1  <<<agg_grid, 256, 0, stream>>>(bkt, counts, (const unsigned*)x_bf,
                                           (const uint2*)s_bf,
                                           (unsigned*)Ax, (uint2*)As);
    k_gemm_r<<<dim3(gr_grid, 2), 256, 0, stream>>>(Ax, As, Wru_bf, b_ru, s_bf, rs2);
    k_agg2  <<<agg_grid, 256, 0, stream>>>(bkt, counts, (const uint2*)rs2,
                                           (uint2*)Ars);
    k_gemm_uc<<<dim3(guc_grid, 2), 256, 0, stream>>>(Ax, As, Ars, Wru_bf, Wc_bf,
                                                     b_ru, b_c, s_bf, out1, out2);
}